// Round 14
// baseline (105.558 us; speedup 1.0000x reference)
//
#include <hip/hip_runtime.h>

// Sliding-window attention, B=2 S=2048 E=1024 H=16 D=64 WINDOW=128.
// Pipeline: bf16 cvt (WEIGHTS ONLY) -> fused QKV GEMM reading fp32 q/k/v
// directly (reg-staged A with in-flight fp32->bf16 convert, write-late;
// B via global_load_lds; counted-vmcnt 2-barrier core; V stored transposed
// + key-permuted) -> banded attention (LDS-staged K/V, counted-vmcnt gates,
// swapped QK^T, lane-local softmax, permuted-k PV) -> output GEMM (fp32 out).

#define S_LEN 2048
#define EMB   1024
#define NHEAD 16
#define HDIM  64
#define MROWS 4096   // B*S

typedef __attribute__((ext_vector_type(4))) float f32x4;
typedef __attribute__((ext_vector_type(8))) short bf16x8;

__device__ __forceinline__ unsigned short f2bf(float x){
  union { float f; unsigned u; } un; un.f = x;
  unsigned u = un.u;
  unsigned r = (u + 0x7FFFu + ((u >> 16) & 1u)) >> 16;  // RNE
  return (unsigned short)r;
}

// ---------------- fp32 -> bf16 conversion (weights only) ----------------
__global__ __launch_bounds__(256) void cvt4_kernel(
    const float4* __restrict__ s0, const float4* __restrict__ s1,
    const float4* __restrict__ s2, const float4* __restrict__ s3,
    unsigned long long* __restrict__ d0, unsigned long long* __restrict__ d1,
    unsigned long long* __restrict__ d2, unsigned long long* __restrict__ d3)
{
  int i = blockIdx.x * 256 + threadIdx.x;
  const float4* s = (blockIdx.y == 0) ? s0 : (blockIdx.y == 1) ? s1 :
                    (blockIdx.y == 2) ? s2 : s3;
  unsigned long long* d = (blockIdx.y == 0) ? d0 : (blockIdx.y == 1) ? d1 :
                          (blockIdx.y == 2) ? d2 : d3;
  float4 v = s[i];
  d[i] = (unsigned long long)f2bf(v.x)
       | ((unsigned long long)f2bf(v.y) << 16)
       | ((unsigned long long)f2bf(v.z) << 32)
       | ((unsigned long long)f2bf(v.w) << 48);
}

// ---------------- async global->LDS (16B per lane) ----------------
__device__ __forceinline__ void async_copy16(const unsigned short* g, unsigned short* l){
  __builtin_amdgcn_global_load_lds(
      (const __attribute__((address_space(1))) unsigned int*)(const void*)g,
      (__attribute__((address_space(3))) unsigned int*)(void*)l,
      16, 0, 0);
}

// ---------------- 128x128xK GEMM core, counted-vmcnt 2-barrier ----------
// (bf16 A and B via global_load_lds; used by out_gemm)
__device__ __forceinline__ void gemm_core_128(
    const unsigned short* __restrict__ A,
    const unsigned short* __restrict__ Bw,
    unsigned short* lds,   // 4*8192 shorts: As0 Bs0 As1 Bs1
    int tile_m, int tile_n, f32x4 acc[4][4])
{
  const int tid  = threadIdx.x;
  const int lane = tid & 63;
  const int wid  = tid >> 6;
  const int wm = wid >> 1, wn = wid & 1;
  const int c = lane & 15, g = lane >> 4;
  const int srow = lane >> 3, sch = lane & 7;

  unsigned short* As0 = lds;
  unsigned short* Bs0 = lds + 8192;
  unsigned short* As1 = lds + 16384;
  unsigned short* Bs1 = lds + 24576;

  auto stage = [&](unsigned short* As, unsigned short* Bs, int k0){
#pragma unroll
    for (int i = 0; i < 4; ++i){
      int row = (wid*4 + i)*8 + srow;
      int chg = sch ^ (row & 7);               // pre-swizzled source chunk
      async_copy16(A  + (size_t)(tile_m + row)*EMB + k0 + chg*8, As + (wid*4 + i)*512);
      async_copy16(Bw + (size_t)(tile_n + row)*EMB + k0 + chg*8, Bs + (wid*4 + i)*512);
    }
  };

  auto compute = [&](const unsigned short* As, const unsigned short* Bs){
#pragma unroll
    for (int kk = 0; kk < 2; ++kk){
      bf16x8 af[4], bfv[4];
#pragma unroll
      for (int mi = 0; mi < 4; ++mi){
        int row = wm*64 + mi*16 + c;
        int ch  = (kk*4 + g) ^ (row & 7);
        af[mi] = *(const bf16x8*)&As[row*64 + ch*8];
      }
#pragma unroll
      for (int ni = 0; ni < 4; ++ni){
        int row = wn*64 + ni*16 + c;
        int ch  = (kk*4 + g) ^ (row & 7);
        bfv[ni] = *(const bf16x8*)&Bs[row*64 + ch*8];
      }
#pragma unroll
      for (int mi = 0; mi < 4; ++mi)
#pragma unroll
        for (int ni = 0; ni < 4; ++ni)
          acc[mi][ni] = __builtin_amdgcn_mfma_f32_16x16x32_bf16(af[mi], bfv[ni], acc[mi][ni], 0, 0, 0);
    }
  };

  stage(As0, Bs0, 0);
  for (int t = 0; t < 16; ++t){
    const unsigned short* Ac = (t & 1) ? As1 : As0;
    const unsigned short* Bc = (t & 1) ? Bs1 : Bs0;
    unsigned short*       An = (t & 1) ? As0 : As1;
    unsigned short*       Bn = (t & 1) ? Bs0 : Bs1;
    if (t < 15){
      stage(An, Bn, (t + 1) * 64);
      asm volatile("s_waitcnt vmcnt(8)" ::: "memory");  // tile t resident
    } else {
      asm volatile("s_waitcnt vmcnt(0)" ::: "memory");
    }
    asm volatile("s_barrier" ::: "memory");
    compute(Ac, Bc);
    asm volatile("s_barrier" ::: "memory");   // all waves done reading cur
  }
}

// ---------------- fused QKV projection (fp32 A, 128^2 tiles) ----------------
// A (q/k/v) read as fp32 and converted in-flight: issue 8 dwordx4 loads for
// tile t+1 before compute(t); after compute, convert (f2bf) and ds_write_b128
// into the SAME swizzled bf16 LDS layout (chunk C holds source chunk
// (C&7)^(row&7)); B (weights) staged via global_load_lds as before.
// z=0: Q -> [B,H,S,D]; z=1: K -> [B,H,S,D]
// z=2: V -> transposed [B,H,D,S], keys permuted within 32-blocks:
//   pos(s) = (s&~31) | ((s>>2)&3)*8 | ((s>>4)&1)*4 | (s&3)
__global__ __launch_bounds__(256) void qkv_gemm_kernel(
    const float* __restrict__ qf, const float* __restrict__ kf,
    const float* __restrict__ vf,
    const unsigned short* __restrict__ Wqb, const unsigned short* __restrict__ Wkb,
    const unsigned short* __restrict__ Wvb,
    const float* __restrict__ bq, const float* __restrict__ bk,
    const float* __restrict__ bv,
    unsigned short* __restrict__ Qp, unsigned short* __restrict__ Kp,
    unsigned short* __restrict__ Vt)
{
  __shared__ __align__(16) unsigned short lds[4*8192];  // As0 Bs0 As1 Bs1
  const int z = blockIdx.z;
  const float*          Af   = (z == 0) ? qf  : (z == 1) ? kf  : vf;
  const unsigned short* W    = (z == 0) ? Wqb : (z == 1) ? Wkb : Wvb;
  const float*          bias = (z == 0) ? bq  : (z == 1) ? bk  : bv;
  const int tile_m = blockIdx.x * 128;
  const int tile_n = blockIdx.y * 128;

  const int tid  = threadIdx.x;
  const int lane = tid & 63;
  const int wid  = tid >> 6;
  const int wm = wid >> 1, wn = wid & 1;
  const int c = lane & 15, g = lane >> 4;
  const int srow = lane >> 3, sch = lane & 7;

  unsigned short* As0 = lds;
  unsigned short* Bs0 = lds + 8192;
  unsigned short* As1 = lds + 16384;
  unsigned short* Bs1 = lds + 24576;

  f32x4 acc[4][4] = {};
  float4 areg[8];                      // in-flight fp32 A chunks (2 per i)

  // this thread's 4 LDS chunks: C = (wid*4+i)*64 + lane; row=C>>3, pos=C&7
  auto loadA = [&](int k0){
#pragma unroll
    for (int i = 0; i < 4; ++i){
      int C = (wid*4 + i)*64 + lane;
      int r = C >> 3, cs = (C & 7) ^ (r & 7);   // pre-swizzled source chunk
      const float* src = Af + (size_t)(tile_m + r)*EMB + k0 + cs*8;
      areg[i*2+0] = *(const float4*)(src);
      areg[i*2+1] = *(const float4*)(src + 4);
    }
  };
  auto writeA = [&](unsigned short* As){
#pragma unroll
    for (int i = 0; i < 4; ++i){
      int C = (wid*4 + i)*64 + lane;
      union { unsigned short s[8]; bf16x8 v; } u;
      const float* f = (const float*)&areg[i*2];
#pragma unroll
      for (int j = 0; j < 8; ++j) u.s[j] = f2bf(f[j]);
      *(bf16x8*)&As[C*8] = u.v;
    }
  };
  auto stageB = [&](unsigned short* Bs, int k0){
#pragma unroll
    for (int i = 0; i < 4; ++i){
      int row = (wid*4 + i)*8 + srow;
      int chg = sch ^ (row & 7);
      async_copy16(W + (size_t)(tile_n + row)*EMB + k0 + chg*8, Bs + (wid*4 + i)*512);
    }
  };
  auto compute = [&](const unsigned short* As, const unsigned short* Bs){
#pragma unroll
    for (int kk = 0; kk < 2; ++kk){
      bf16x8 af[4], bfv[4];
#pragma unroll
      for (int mi = 0; mi < 4; ++mi){
        int row = wm*64 + mi*16 + c;
        int ch  = (kk*4 + g) ^ (row & 7);
        af[mi] = *(const bf16x8*)&As[row*64 + ch*8];
      }
#pragma unroll
      for (int ni = 0; ni < 4; ++ni){
        int row = wn*64 + ni*16 + c;
        int ch  = (kk*4 + g) ^ (row & 7);
        bfv[ni] = *(const bf16x8*)&Bs[row*64 + ch*8];
      }
#pragma unroll
      for (int mi = 0; mi < 4; ++mi)
#pragma unroll
        for (int ni = 0; ni < 4; ++ni)
          acc[mi][ni] = __builtin_amdgcn_mfma_f32_16x16x32_bf16(af[mi], bfv[ni], acc[mi][ni], 0, 0, 0);
    }
  };

  // prologue: tile 0
  loadA(0);
  stageB(Bs0, 0);
  writeA(As0);                                   // compiler waits A-reg deps
  asm volatile("s_waitcnt vmcnt(0) lgkmcnt(0)" ::: "memory");
  asm volatile("s_barrier" ::: "memory");

  for (int t = 0; t < 16; ++t){
    const unsigned short* Ac = (t & 1) ? As1 : As0;
    const unsigned short* Bc = (t & 1) ? Bs1 : Bs0;
    unsigned short*       An = (t & 1) ? As0 : As1;
    unsigned short*       Bn = (t & 1) ? Bs0 : Bs1;
    if (t < 15){
      loadA((t + 1) * 64);                       // fp32 loads fly under compute
      stageB(Bn, (t + 1) * 64);
    }
    compute(Ac, Bc);
    if (t < 15){
      writeA(An);                                // waits A-regs via reg deps
      asm volatile("s_waitcnt vmcnt(0) lgkmcnt(0)" ::: "memory");  // B + writes
    }
    asm volatile("s_barrier" ::: "memory");      // publish next / free cur
  }

  if (z < 2){
    unsigned short* O = (z == 0) ? Qp : Kp;
#pragma unroll
    for (int mi = 0; mi < 4; ++mi){
      int m0 = tile_m + wm*64 + mi*16 + g*4;
#pragma unroll
      for (int ni = 0; ni < 4; ++ni){
        int n = tile_n + wn*64 + ni*16 + c;
        int h = n >> 6, d = n & 63;
        float bvn = bias[n];
#pragma unroll
        for (int j = 0; j < 4; ++j){
          int m = m0 + j;
          int bb = m >> 11, ss = m & 2047;
          O[(((size_t)bb*NHEAD + h)*S_LEN + ss)*HDIM + d] = f2bf(acc[mi][ni][j] + bvn);
        }
      }
    }
  } else {
#pragma unroll
    for (int mi = 0; mi < 4; ++mi){
      int m0 = tile_m + wm*64 + mi*16 + g*4;
      int bb = m0 >> 11, ss = m0 & 2047;
      // key-permuted position (ss % 4 == 0, quad stays one 8B store)
      int ssp = (ss & ~31) | (((ss >> 2) & 3) << 3) | (((ss >> 4) & 1) << 2);
#pragma unroll
      for (int ni = 0; ni < 4; ++ni){
        int n = tile_n + wn*64 + ni*16 + c;
        int h = n >> 6, d = n & 63;
        float bvn = bias[n];
        unsigned long long pk =
              (unsigned long long)f2bf(acc[mi][ni][0] + bvn)
            | ((unsigned long long)f2bf(acc[mi][ni][1] + bvn) << 16)
            | ((unsigned long long)f2bf(acc[mi][ni][2] + bvn) << 32)
            | ((unsigned long long)f2bf(acc[mi][ni][3] + bvn) << 48);
        *(unsigned long long*)&Vt[(((size_t)bb*NHEAD + h)*HDIM + d)*S_LEN + ssp] = pk;
      }
    }
  }
}

// ---------------- banded attention: LDS-staged K/V, counted-vmcnt gates ----
__global__ __launch_bounds__(256) void attn_kernel(
    const unsigned short* __restrict__ Qp, const unsigned short* __restrict__ Kp,
    const unsigned short* __restrict__ Vt, unsigned short* __restrict__ X2)
{
  __shared__ __align__(16) unsigned short Kl[2][64*64];
  __shared__ __align__(16) unsigned short Vl[2][64*64];

  const int tid = threadIdx.x, lane = tid & 63, w = tid >> 6;
  const int c = lane & 15, g = lane >> 4;
  // XCD swizzle (1024 = 8 XCD x 128)
  int bid0 = blockIdx.x;
  int bid = (bid0 & 7) * 128 + (bid0 >> 3);
  const int bh = bid >> 5, qt = bid & 31;
  const int qbase = qt * 64;
  const int qw = qbase + w * 16;
  const int qi = qw + c;

  const unsigned short* Kbh = Kp + (size_t)bh * S_LEN * HDIM;
  const unsigned short* Vbh = Vt + (size_t)bh * HDIM * S_LEN;

  const unsigned short* Qb = Qp + ((size_t)bh*S_LEN + qw + c)*HDIM;
  bf16x8 aq0 = *(const bf16x8*)(Qb + g*8);
  bf16x8 aq1 = *(const bf16x8*)(Qb + 32 + g*8);

  f32x4 accO[4] = {};
  float lsum = 0.f;
  const float SC = 0.18033688011112042f;  // (1/sqrt(64)) * log2(e)

  int t0 = qbase - 128; if (t0 < 0) t0 = 0;
  int t1 = qbase + 192; if (t1 > S_LEN) t1 = S_LEN;

  const int srow = lane >> 3;
  const int sch  = (lane & 7) ^ srow;

  auto stage = [&](int buf, int kt){           // 4 loads/thread
#pragma unroll
    for (int i = 0; i < 2; ++i){
      int r0 = w*16 + i*8;
      async_copy16(Kbh + (size_t)(kt + r0 + srow)*HDIM + sch*8, &Kl[buf][r0*64]);
      async_copy16(Vbh + (size_t)(r0 + srow)*S_LEN + kt + sch*8, &Vl[buf][r0*64]);
    }
  };

  auto compute = [&](int buf, int kt){
    f32x4 s[4];
    __builtin_amdgcn_s_setprio(1);
#pragma unroll
    for (int f = 0; f < 4; ++f){
      const unsigned short* Kr = &Kl[buf][(f*16 + c)*64];
      bf16x8 k0 = *(const bf16x8*)(Kr + ((    g) ^ (c & 7))*8);
      bf16x8 k1 = *(const bf16x8*)(Kr + ((4 + g) ^ (c & 7))*8);
      f32x4 a = {0.f, 0.f, 0.f, 0.f};
      a = __builtin_amdgcn_mfma_f32_16x16x32_bf16(k0, aq0, a, 0, 0, 0);
      a = __builtin_amdgcn_mfma_f32_16x16x32_bf16(k1, aq1, a, 0, 0, 0);
      s[f] = a;
    }
    __builtin_amdgcn_s_setprio(0);

    float p[4][4];
    bool nomask = (kt >= qw - 113) && (kt <= qw + 65);
    if (nomask){
#pragma unroll
      for (int f = 0; f < 4; ++f)
#pragma unroll
        for (int j = 0; j < 4; ++j){
          p[f][j] = exp2f(s[f][j] * SC);
          lsum += p[f][j];
        }
    } else {
#pragma unroll
      for (int f = 0; f < 4; ++f)
#pragma unroll
        for (int j = 0; j < 4; ++j){
          int dlt = qi - (kt + f*16 + g*4 + j);
          float e = exp2f(s[f][j] * SC);
          e = (dlt <= 128 && dlt >= -128) ? e : 0.f;
          p[f][j] = e;
          lsum += e;
        }
    }

    union { unsigned u[4]; bf16x8 v; } A0, A1;
    A0.u[0] = (unsigned)f2bf(p[0][0]) | ((unsigned)f2bf(p[0][1]) << 16);
    A0.u[1] = (unsigned)f2bf(p[0][2]) | ((unsigned)f2bf(p[0][3]) << 16);
    A0.u[2] = (unsigned)f2bf(p[1][0]) | ((unsigned)f2bf(p[1][1]) << 16);
    A0.u[3] = (unsigned)f2bf(p[1][2]) | ((unsigned)f2bf(p[1][3]) << 16);
    A1.u[0] = (unsigned)f2bf(p[2][0]) | ((unsigned)f2bf(p[2][1]) << 16);
    A1.u[1] = (unsigned)f2bf(p[2][2]) | ((unsigned)f2bf(p[2][3]) << 16);
    A1.u[2] = (unsigned)f2bf(p[3][0]) | ((unsigned)f2bf(p[3][1]) << 16);
    A1.u[3] = (unsigned)f2bf(p[3][2]) | ((unsigned)f2bf(p[3][3]) << 16);

    __builtin_amdgcn_s_setprio(1);
#pragma unroll
    for (int dblk = 0; dblk < 4; ++dblk){
      const unsigned short* Vr = &Vl[buf][(dblk*16 + c)*64];
      bf16x8 v0 = *(const bf16x8*)(Vr + ((    g) ^ (c & 7))*8);
      bf16x8 v1 = *(const bf16x8*)(Vr + ((4 + g) ^ (c & 7))*8);
      accO[dblk] = __builtin_amdgcn_mfma_f32_16x16x32_bf16(A0.v, v0, accO[dblk], 0, 0, 0);
      accO[dblk] = __builtin_amdgcn_mfma_f32_16x16x32_bf16(A1.v, v1, accO[dblk], 0, 0, 0);
    }
    __builtin_amdgcn_s_setprio(0);
  };

  stage(0, t0);
  int cur = 0;
  for (int kt = t0; kt < t1; kt += 64){
    if (kt + 64 < t1){
      stage(cur ^ 1, kt + 64);
      asm volatile("s_waitcnt vmcnt(4)" ::: "memory");  // tile kt resident
    } else {
      asm volatile("s_waitcnt vmcnt(0)" ::: "memory");
    }
    asm volatile("s_barrier" ::: "memory");
    bool active = (kt + 63 >= qw - 128) && (kt <= qw + 143);
    if (active) compute(cur, kt);
    asm volatile("s_barrier" ::: "memory");   // cur free for overwrite
    cur ^= 1;
  }

  lsum += __shfl_xor(lsum, 16);
  lsum += __shfl_xor(lsum, 32);
  float rl[4];
#pragma unroll
  for (int j = 0; j < 4; ++j)
    rl[j] = 1.f / __shfl(lsum, g*4 + j);

  const int b_ = bh >> 4, h_ = bh & 15;
#pragma unroll
  for (int dblk = 0; dblk < 4; ++dblk)
#pragma unroll
    for (int j = 0; j < 4; ++j){
      int s_ = qw + g*4 + j, d_ = dblk*16 + c;
      X2[((size_t)(b_*S_LEN + s_))*EMB + h_*64 + d_] = f2bf(accO[dblk][j] * rl[j]);
    }
}

// ---------------- output projection (fp32 out) ----------------
__global__ __launch_bounds__(256) void out_gemm_kernel(
    const unsigned short* __restrict__ X2, const unsigned short* __restrict__ Wob,
    const float* __restrict__ bo, float* __restrict__ out)
{
  __shared__ __align__(16) unsigned short lds[4*8192];
  const int tile_m = blockIdx.x * 128;
  const int tile_n = blockIdx.y * 128;
  f32x4 acc[4][4] = {};
  gemm_core_128(X2, Wob, lds, tile_m, tile_n, acc);

  const int tid = threadIdx.x, lane = tid & 63, wid = tid >> 6;
  const int wm = wid >> 1, wn = wid & 1, c = lane & 15, g = lane >> 4;
#pragma unroll
  for (int mi = 0; mi < 4; ++mi){
    int m0 = tile_m + wm*64 + mi*16 + g*4;
#pragma unroll
    for (int ni = 0; ni < 4; ++ni){
      int n = tile_n + wn*64 + ni*16 + c;
      float bvn = bo[n];
#pragma unroll
      for (int j = 0; j < 4; ++j)
        out[(size_t)(m0 + j)*EMB + n] = acc[mi][ni][j] + bvn;
    }
  }
}

extern "C" void kernel_launch(void* const* d_in, const int* in_sizes, int n_in,
                              void* d_out, int out_size, void* d_ws, size_t ws_size,
                              hipStream_t stream)
{
  const float* q  = (const float*)d_in[0];
  const float* k  = (const float*)d_in[1];
  const float* v  = (const float*)d_in[2];
  const float* Wq = (const float*)d_in[3];
  const float* bq = (const float*)d_in[4];
  const float* Wk = (const float*)d_in[5];
  const float* bk = (const float*)d_in[6];
  const float* Wv = (const float*)d_in[7];
  const float* bv = (const float*)d_in[8];
  const float* Wo = (const float*)d_in[9];
  const float* bo = (const float*)d_in[10];
  float* out = (float*)d_out;

  // workspace layout (ushort elements)
  unsigned short* ws = (unsigned short*)d_ws;
  unsigned short* X2  = ws;                    // 4096*1024 bf16
  unsigned short* Wqb = ws + 12582912;         // 1024*1024 each
  unsigned short* Wkb = ws + 13631488;
  unsigned short* Wvb = ws + 14680064;
  unsigned short* Wob = ws + 15728640;
  unsigned short* Qp  = ws + 16777216;         // [B,H,S,D]
  unsigned short* Kp  = ws + 20971520;         // [B,H,S,D]
  unsigned short* Vt  = ws + 25165824;         // [B,H,D,S] key-permuted

  // fp32 -> bf16: weights only
  cvt4_kernel<<<dim3(1024, 4), 256, 0, stream>>>(
      (const float4*)Wq, (const float4*)Wk, (const float4*)Wv, (const float4*)Wo,
      (unsigned long long*)Wqb, (unsigned long long*)Wkb,
      (unsigned long long*)Wvb, (unsigned long long*)Wob);

  // fused QKV projection (fp32 q/k/v consumed directly)
  qkv_gemm_kernel<<<dim3(32, 8, 3), 256, 0, stream>>>(
      q, k, v, Wqb, Wkb, Wvb, bq, bk, bv, Qp, Kp, Vt);

  // banded attention -> X2 [B,S,E] bf16
  attn_kernel<<<1024, 256, 0, stream>>>(Qp, Kp, Vt, X2);

  // output projection -> fp32
  out_gemm_kernel<<<dim3(32, 8), 256, 0, stream>>>(X2, Wob, bo, out);
}

// Round 15
// 83.550 us; speedup vs baseline: 1.2634x; 1.2634x over previous
//
#include <hip/hip_runtime.h>
#include <hip/hip_bf16.h>

// Sliding-window attention, B=2 S=2048 E=1024 H=16 D=64 WINDOW=128.
// Pipeline: fp32->bf16 cvt (2 fused launches) -> fused QKV GEMM (single
// 4096x3072 GEMM, 256^2 tile, 8 waves, counted-vmcnt 2-barrier pipeline;
// V stored transposed + key-permuted) -> banded attention (LDS-staged K/V,
// counted-vmcnt gates, swapped QK^T, lane-local softmax with v_cvt_pk
// bf16 pack, permuted-k PV) -> output GEMM (128^2 counted-vmcnt, fp32 out).

#define S_LEN 2048
#define EMB   1024
#define NHEAD 16
#define HDIM  64
#define MROWS 4096   // B*S

typedef __attribute__((ext_vector_type(4))) float f32x4;
typedef __attribute__((ext_vector_type(8))) short bf16x8;

__device__ __forceinline__ unsigned short f2bf(float x){
  union { float f; unsigned u; } un; un.f = x;
  unsigned u = un.u;
  unsigned r = (u + 0x7FFFu + ((u >> 16) & 1u)) >> 16;  // RNE
  return (unsigned short)r;
}

// packed RNE f32x2 -> bf16x2 (compiler emits v_cvt_pk_bf16_f32 on gfx950)
__device__ __forceinline__ unsigned cvtpk(float lo, float hi){
  __hip_bfloat162 h = __float22bfloat162_rn(make_float2(lo, hi));
  union { __hip_bfloat162 h2; unsigned u; } cv; cv.h2 = h;
  return cv.u;
}

// ---------------- fp32 -> bf16 conversion (fused, vectorized) ----------------
__global__ __launch_bounds__(256) void cvt3_kernel(
    const float4* __restrict__ s0, const float4* __restrict__ s1,
    const float4* __restrict__ s2,
    unsigned long long* __restrict__ d0, unsigned long long* __restrict__ d1,
    unsigned long long* __restrict__ d2)
{
  int i = blockIdx.x * 256 + threadIdx.x;
  const float4* s = (blockIdx.y == 0) ? s0 : (blockIdx.y == 1) ? s1 : s2;
  unsigned long long* d = (blockIdx.y == 0) ? d0 : (blockIdx.y == 1) ? d1 : d2;
  float4 v = s[i];
  d[i] = (unsigned long long)cvtpk(v.x, v.y)
       | ((unsigned long long)cvtpk(v.z, v.w) << 32);
}

__global__ __launch_bounds__(256) void cvt4_kernel(
    const float4* __restrict__ s0, const float4* __restrict__ s1,
    const float4* __restrict__ s2, const float4* __restrict__ s3,
    unsigned long long* __restrict__ d0, unsigned long long* __restrict__ d1,
    unsigned long long* __restrict__ d2, unsigned long long* __restrict__ d3)
{
  int i = blockIdx.x * 256 + threadIdx.x;
  const float4* s = (blockIdx.y == 0) ? s0 : (blockIdx.y == 1) ? s1 :
                    (blockIdx.y == 2) ? s2 : s3;
  unsigned long long* d = (blockIdx.y == 0) ? d0 : (blockIdx.y == 1) ? d1 :
                          (blockIdx.y == 2) ? d2 : d3;
  float4 v = s[i];
  d[i] = (unsigned long long)cvtpk(v.x, v.y)
       | ((unsigned long long)cvtpk(v.z, v.w) << 32);
}

// ---------------- async global->LDS (16B per lane) ----------------
__device__ __forceinline__ void async_copy16(const unsigned short* g, unsigned short* l){
  __builtin_amdgcn_global_load_lds(
      (const __attribute__((address_space(1))) unsigned int*)(const void*)g,
      (__attribute__((address_space(3))) unsigned int*)(void*)l,
      16, 0, 0);
}

// ---------------- 128x128xK GEMM core, counted-vmcnt 2-barrier ----------
__device__ __forceinline__ void gemm_core_128(
    const unsigned short* __restrict__ A,
    const unsigned short* __restrict__ Bw,
    unsigned short* lds,   // 4*8192 shorts: As0 Bs0 As1 Bs1
    int tile_m, int tile_n, f32x4 acc[4][4])
{
  const int tid  = threadIdx.x;
  const int lane = tid & 63;
  const int wid  = tid >> 6;
  const int wm = wid >> 1, wn = wid & 1;
  const int c = lane & 15, g = lane >> 4;
  const int srow = lane >> 3, sch = lane & 7;

  unsigned short* As0 = lds;
  unsigned short* Bs0 = lds + 8192;
  unsigned short* As1 = lds + 16384;
  unsigned short* Bs1 = lds + 24576;

  auto stage = [&](unsigned short* As, unsigned short* Bs, int k0){
#pragma unroll
    for (int i = 0; i < 4; ++i){
      int row = (wid*4 + i)*8 + srow;
      int chg = sch ^ (row & 7);               // pre-swizzled source chunk
      async_copy16(A  + (size_t)(tile_m + row)*EMB + k0 + chg*8, As + (wid*4 + i)*512);
      async_copy16(Bw + (size_t)(tile_n + row)*EMB + k0 + chg*8, Bs + (wid*4 + i)*512);
    }
  };

  auto compute = [&](const unsigned short* As, const unsigned short* Bs){
#pragma unroll
    for (int kk = 0; kk < 2; ++kk){
      bf16x8 af[4], bfv[4];
#pragma unroll
      for (int mi = 0; mi < 4; ++mi){
        int row = wm*64 + mi*16 + c;
        int ch  = (kk*4 + g) ^ (row & 7);
        af[mi] = *(const bf16x8*)&As[row*64 + ch*8];
      }
#pragma unroll
      for (int ni = 0; ni < 4; ++ni){
        int row = wn*64 + ni*16 + c;
        int ch  = (kk*4 + g) ^ (row & 7);
        bfv[ni] = *(const bf16x8*)&Bs[row*64 + ch*8];
      }
#pragma unroll
      for (int mi = 0; mi < 4; ++mi)
#pragma unroll
        for (int ni = 0; ni < 4; ++ni)
          acc[mi][ni] = __builtin_amdgcn_mfma_f32_16x16x32_bf16(af[mi], bfv[ni], acc[mi][ni], 0, 0, 0);
    }
  };

  stage(As0, Bs0, 0);
  for (int t = 0; t < 16; ++t){
    const unsigned short* Ac = (t & 1) ? As1 : As0;
    const unsigned short* Bc = (t & 1) ? Bs1 : Bs0;
    unsigned short*       An = (t & 1) ? As0 : As1;
    unsigned short*       Bn = (t & 1) ? Bs0 : Bs1;
    if (t < 15){
      stage(An, Bn, (t + 1) * 64);
      asm volatile("s_waitcnt vmcnt(8)" ::: "memory");  // tile t resident
    } else {
      asm volatile("s_waitcnt vmcnt(0)" ::: "memory");
    }
    asm volatile("s_barrier" ::: "memory");
    compute(Ac, Bc);
    asm volatile("s_barrier" ::: "memory");   // all waves done reading cur
  }
}

// ---------------- fused QKV projection: one 4096x3072 GEMM ----------------
// 256x256 tile, BK=64, 8 waves (2M x 4N), 128KB dbuf LDS, counted-vmcnt
// pipeline with two barriers per K-tile (round-8 derivation).
// n < 1024: Q -> [B,H,S,D]; n < 2048: K -> [B,H,S,D];
// n < 3072: V -> transposed [B,H,D,S], keys permuted within 32-blocks:
//   pos(s) = (s&~31) | ((s>>2)&3)*8 | ((s>>4)&1)*4 | (s&3)
__global__ __launch_bounds__(512, 2) void qkv_gemm_kernel(
    const unsigned short* __restrict__ qb, const unsigned short* __restrict__ kb2,
    const unsigned short* __restrict__ vb,
    const unsigned short* __restrict__ Wqb, const unsigned short* __restrict__ Wkb,
    const unsigned short* __restrict__ Wvb,
    const float* __restrict__ bq, const float* __restrict__ bk,
    const float* __restrict__ bv,
    unsigned short* __restrict__ Qp, unsigned short* __restrict__ Kp,
    unsigned short* __restrict__ Vt)
{
  __shared__ __align__(16) unsigned short lds[2][2][256*64];  // [buf][A/B][r*64+k]

  const int tid = threadIdx.x, lane = tid & 63, wid = tid >> 6;  // wid 0..7
  const int wm = wid >> 2, wn = wid & 3;       // 2M x 4N wave grid
  const int c = lane & 15, g = lane >> 4;
  const int srow = lane >> 3, sch = lane & 7;

  // XCD swizzle over 192 blocks (192 % 8 == 0 -> bijective)
  int bid  = blockIdx.x;
  int bid2 = (bid & 7) * 24 + (bid >> 3);
  const int mx = bid2 & 15, ny = bid2 >> 4;    // 16 m-tiles x 12 n-tiles
  const int z  = ny >> 2;                      // 0:Q 1:K 2:V (block-uniform)
  const int tile_m = mx * 256;
  const int nloc   = (ny & 3) * 256;           // proj-local n base

  const unsigned short* A = (z == 0) ? qb  : (z == 1) ? kb2 : vb;
  const unsigned short* W = (z == 0) ? Wqb : (z == 1) ? Wkb : Wvb;
  const float*       bias = (z == 0) ? bq  : (z == 1) ? bk  : bv;

  const unsigned short* Asrc = A + (size_t)tile_m * EMB;
  const unsigned short* Bsrc = W + (size_t)nloc * EMB;

  f32x4 acc[8][4] = {};

  // chunk-p stage: 8 A-rows + 8 B-rows per wave (2 loads/thread)
  auto stageP = [&](int b, int k0, int p){
    int row = wid*32 + p*8 + srow;
    int ch  = sch ^ (row & 7);                 // pre-swizzled source chunk
    async_copy16(Asrc + (size_t)row*EMB + k0 + ch*8, &lds[b][0][(wid*32 + p*8)*64]);
    async_copy16(Bsrc + (size_t)row*EMB + k0 + ch*8, &lds[b][1][(wid*32 + p*8)*64]);
  };

  // prologue: tile 0 fully staged (8 loads/thread)
  stageP(0, 0, 0); stageP(0, 0, 1); stageP(0, 0, 2); stageP(0, 0, 3);

  for (int t = 0; t < 16; ++t){
    const int cb = t & 1, nb = cb ^ 1;
    const bool pre = (t < 15);
    const int k1 = (t + 1) * 64;

    // gate: tile t resident for all waves; 2 fresh loads stay in flight
    if (pre){
      stageP(nb, k1, 0);
      asm volatile("s_waitcnt vmcnt(2)" ::: "memory");
    } else {
      asm volatile("s_waitcnt vmcnt(0)" ::: "memory");
    }
    asm volatile("s_barrier" ::: "memory");

    // B-frags for the whole K-tile (held in regs across phases)
    bf16x8 bfr[4][2];
#pragma unroll
    for (int ni = 0; ni < 4; ++ni)
#pragma unroll
      for (int kk = 0; kk < 2; ++kk){
        int row = wn*64 + ni*16 + c;
        int ch  = (kk*4 + g) ^ (row & 7);
        bfr[ni][kk] = *(const bf16x8*)&lds[cb][1][row*64 + ch*8];
      }

#pragma unroll
    for (int p = 0; p < 4; ++p){
      bf16x8 af[2][2];
#pragma unroll
      for (int mi = 0; mi < 2; ++mi)
#pragma unroll
        for (int kk = 0; kk < 2; ++kk){
          int row = wm*128 + (p*2 + mi)*16 + c;
          int ch  = (kk*4 + g) ^ (row & 7);
          af[mi][kk] = *(const bf16x8*)&lds[cb][0][row*64 + ch*8];
        }
      if (pre && p < 3) stageP(nb, k1, p + 1);  // spread VMEM issue
      __builtin_amdgcn_s_setprio(1);
#pragma unroll
      for (int kk = 0; kk < 2; ++kk)
#pragma unroll
        for (int mi = 0; mi < 2; ++mi)
#pragma unroll
          for (int ni = 0; ni < 4; ++ni)
            acc[p*2 + mi][ni] = __builtin_amdgcn_mfma_f32_16x16x32_bf16(
                af[mi][kk], bfr[ni][kk], acc[p*2 + mi][ni], 0, 0, 0);
      __builtin_amdgcn_s_setprio(0);
    }
    // all waves done reading cb (ds_reads drained via MFMA deps above)
    asm volatile("s_barrier" ::: "memory");
  }

  // epilogue
  if (z < 2){
    unsigned short* O = (z == 0) ? Qp : Kp;
#pragma unroll
    for (int mf = 0; mf < 8; ++mf){
      int m0 = tile_m + wm*128 + mf*16 + g*4;
      int bb = m0 >> 11, ss = m0 & 2047;
#pragma unroll
      for (int ni = 0; ni < 4; ++ni){
        int nn = nloc + wn*64 + ni*16 + c;
        int h = nn >> 6, d = nn & 63;
        float bvn = bias[nn];
        size_t base = (((size_t)bb*NHEAD + h)*S_LEN + ss)*HDIM + d;
#pragma unroll
        for (int j = 0; j < 4; ++j)
          O[base + (size_t)j*HDIM] = f2bf(acc[mf][ni][j] + bvn);
      }
    }
  } else {
#pragma unroll
    for (int mf = 0; mf < 8; ++mf){
      int m0 = tile_m + wm*128 + mf*16 + g*4;
      int bb = m0 >> 11, ss = m0 & 2047;
      // key-permuted position (ss % 4 == 0, quad stays one 8B store)
      int ssp = (ss & ~31) | (((ss >> 2) & 3) << 3) | (((ss >> 4) & 1) << 2);
#pragma unroll
      for (int ni = 0; ni < 4; ++ni){
        int nn = nloc + wn*64 + ni*16 + c;
        int h = nn >> 6, d = nn & 63;
        float bvn = bias[nn];
        unsigned long long pk =
              (unsigned long long)cvtpk(acc[mf][ni][0] + bvn, acc[mf][ni][1] + bvn)
            | ((unsigned long long)cvtpk(acc[mf][ni][2] + bvn, acc[mf][ni][3] + bvn) << 32);
        *(unsigned long long*)&Vt[(((size_t)bb*NHEAD + h)*HDIM + d)*S_LEN + ssp] = pk;
      }
    }
  }
}

// ---------------- banded attention: LDS-staged K/V, counted-vmcnt gates ----
// 1 block = (b,h, 64 q-rows); 4 waves x 16 q-rows; 64-key tiles shared by
// the block, double-buffered in LDS. Per tile: stage next (4 loads/thread)
// -> vmcnt(4) -> s_barrier -> compute cur -> s_barrier. Swapped QK^T,
// lane-local fixed-max softmax (v_cvt_pk bf16 pack), permuted-k PV.
__global__ __launch_bounds__(256) void attn_kernel(
    const unsigned short* __restrict__ Qp, const unsigned short* __restrict__ Kp,
    const unsigned short* __restrict__ Vt, unsigned short* __restrict__ X2)
{
  __shared__ __align__(16) unsigned short Kl[2][64*64];
  __shared__ __align__(16) unsigned short Vl[2][64*64];

  const int tid = threadIdx.x, lane = tid & 63, w = tid >> 6;
  const int c = lane & 15, g = lane >> 4;
  // XCD swizzle (1024 = 8 XCD x 128)
  int bid0 = blockIdx.x;
  int bid = (bid0 & 7) * 128 + (bid0 >> 3);
  const int bh = bid >> 5, qt = bid & 31;
  const int qbase = qt * 64;
  const int qw = qbase + w * 16;
  const int qi = qw + c;

  const unsigned short* Kbh = Kp + (size_t)bh * S_LEN * HDIM;
  const unsigned short* Vbh = Vt + (size_t)bh * HDIM * S_LEN;

  const unsigned short* Qb = Qp + ((size_t)bh*S_LEN + qw + c)*HDIM;
  bf16x8 aq0 = *(const bf16x8*)(Qb + g*8);
  bf16x8 aq1 = *(const bf16x8*)(Qb + 32 + g*8);

  f32x4 accO[4] = {};
  float lsum = 0.f;
  const float SC = 0.18033688011112042f;  // (1/sqrt(64)) * log2(e)

  int t0 = qbase - 128; if (t0 < 0) t0 = 0;
  int t1 = qbase + 192; if (t1 > S_LEN) t1 = S_LEN;

  const int srow = lane >> 3;
  const int sch  = (lane & 7) ^ srow;

  auto stage = [&](int buf, int kt){           // 4 loads/thread
#pragma unroll
    for (int i = 0; i < 2; ++i){
      int r0 = w*16 + i*8;
      async_copy16(Kbh + (size_t)(kt + r0 + srow)*HDIM + sch*8, &Kl[buf][r0*64]);
      async_copy16(Vbh + (size_t)(r0 + srow)*S_LEN + kt + sch*8, &Vl[buf][r0*64]);
    }
  };

  auto compute = [&](int buf, int kt){
    f32x4 s[4];
    __builtin_amdgcn_s_setprio(1);
#pragma unroll
    for (int f = 0; f < 4; ++f){
      const unsigned short* Kr = &Kl[buf][(f*16 + c)*64];
      bf16x8 k0 = *(const bf16x8*)(Kr + ((    g) ^ (c & 7))*8);
      bf16x8 k1 = *(const bf16x8*)(Kr + ((4 + g) ^ (c & 7))*8);
      f32x4 a = {0.f, 0.f, 0.f, 0.f};
      a = __builtin_amdgcn_mfma_f32_16x16x32_bf16(k0, aq0, a, 0, 0, 0);
      a = __builtin_amdgcn_mfma_f32_16x16x32_bf16(k1, aq1, a, 0, 0, 0);
      s[f] = a;
    }
    __builtin_amdgcn_s_setprio(0);

    float p[4][4];
    bool nomask = (kt >= qw - 113) && (kt <= qw + 65);
    if (nomask){
#pragma unroll
      for (int f = 0; f < 4; ++f)
#pragma unroll
        for (int j = 0; j < 4; ++j){
          p[f][j] = __builtin_amdgcn_exp2f(s[f][j] * SC);
          lsum += p[f][j];
        }
    } else {
#pragma unroll
      for (int f = 0; f < 4; ++f)
#pragma unroll
        for (int j = 0; j < 4; ++j){
          int dlt = qi - (kt + f*16 + g*4 + j);
          float e = __builtin_amdgcn_exp2f(s[f][j] * SC);
          e = (dlt <= 128 && dlt >= -128) ? e : 0.f;
          p[f][j] = e;
          lsum += e;
        }
    }

    // pack p -> bf16 A-frags via v_cvt_pk_bf16_f32 (1 op per pair)
    union { unsigned u[4]; bf16x8 v; } A0, A1;
    A0.u[0] = cvtpk(p[0][0], p[0][1]);
    A0.u[1] = cvtpk(p[0][2], p[0][3]);
    A0.u[2] = cvtpk(p[1][0], p[1][1]);
    A0.u[3] = cvtpk(p[1][2], p[1][3]);
    A1.u[0] = cvtpk(p[2][0], p[2][1]);
    A1.u[1] = cvtpk(p[2][2], p[2][3]);
    A1.u[2] = cvtpk(p[3][0], p[3][1]);
    A1.u[3] = cvtpk(p[3][2], p[3][3]);

    __builtin_amdgcn_s_setprio(1);
#pragma unroll
    for (int dblk = 0; dblk < 4; ++dblk){
      const unsigned short* Vr = &Vl[buf][(dblk*16 + c)*64];
      bf16x8 v0 = *(const bf16x8*)(Vr + ((    g) ^ (c & 7))*8);
      bf16x8 v1 = *(const bf16x8*)(Vr + ((4 + g) ^ (c & 7))*8);
      accO[dblk] = __builtin_amdgcn_mfma_f32_16x16x32_bf16(A0.v, v0, accO[dblk], 0, 0, 0);
      accO[dblk] = __builtin_amdgcn_mfma_f32_16x16x32_bf16(A1.v, v1, accO[dblk], 0, 0, 0);
    }
    __builtin_amdgcn_s_setprio(0);
  };

  stage(0, t0);
  int cur = 0;
  for (int kt = t0; kt < t1; kt += 64){
    if (kt + 64 < t1){
      stage(cur ^ 1, kt + 64);
      asm volatile("s_waitcnt vmcnt(4)" ::: "memory");  // tile kt resident
    } else {
      asm volatile("s_waitcnt vmcnt(0)" ::: "memory");
    }
    asm volatile("s_barrier" ::: "memory");
    bool active = (kt + 63 >= qw - 128) && (kt <= qw + 143);
    if (active) compute(cur, kt);
    asm volatile("s_barrier" ::: "memory");   // cur free for overwrite
    cur ^= 1;
  }

  lsum += __shfl_xor(lsum, 16);
  lsum += __shfl_xor(lsum, 32);
  float rl[4];
#pragma unroll
  for (int j = 0; j < 4; ++j)
    rl[j] = 1.f / __shfl(lsum, g*4 + j);

  const int b_ = bh >> 4, h_ = bh & 15;
#pragma unroll
  for (int dblk = 0; dblk < 4; ++dblk)
#pragma unroll
    for (int j = 0; j < 4; ++j){
      int s_ = qw + g*4 + j, d_ = dblk*16 + c;
      X2[((size_t)(b_*S_LEN + s_))*EMB + h_*64 + d_] = f2bf(accO[dblk][j] * rl[j]);
    }
}

// ---------------- output projection (fp32 out) ----------------
__global__ __launch_bounds__(256) void out_gemm_kernel(
    const unsigned short* __restrict__ X2, const unsigned short* __restrict__ Wob,
    const float* __restrict__ bo, float* __restrict__ out)
{
  __shared__ __align__(16) unsigned short lds[4*8192];
  const int tile_m = blockIdx.x * 128;
  const int tile_n = blockIdx.y * 128;
  f32x4 acc[4][4] = {};
  gemm_core_128(X2, Wob, lds, tile_m, tile_n, acc);

  const int tid = threadIdx.x, lane = tid & 63, wid = tid >> 6;
  const int wm = wid >> 1, wn = wid & 1, c = lane & 15, g = lane >> 4;
#pragma unroll
  for (int mi = 0; mi < 4; ++mi){
    int m0 = tile_m + wm*64 + mi*16 + g*4;
#pragma unroll
    for (int ni = 0; ni < 4; ++ni){
      int n = tile_n + wn*64 + ni*16 + c;
      float bvn = bo[n];
#pragma unroll
      for (int j = 0; j < 4; ++j)
        out[(size_t)(m0 + j)*EMB + n] = acc[mi][ni][j] + bvn;
    }
  }
}

extern "C" void kernel_launch(void* const* d_in, const int* in_sizes, int n_in,
                              void* d_out, int out_size, void* d_ws, size_t ws_size,
                              hipStream_t stream)
{
  const float* q  = (const float*)d_in[0];
  const float* k  = (const float*)d_in[1];
  const float* v  = (const float*)d_in[2];
  const float* Wq = (const float*)d_in[3];
  const float* bq = (const float*)d_in[4];
  const float* Wk = (const float*)d_in[5];
  const float* bk = (const float*)d_in[6];
  const float* Wv = (const float*)d_in[7];
  const float* bv = (const float*)d_in[8];
  const float* Wo = (const float*)d_in[9];
  const float* bo = (const float*)d_in[10];
  float* out = (float*)d_out;

  // workspace layout (ushort elements); total 56 MB
  unsigned short* ws = (unsigned short*)d_ws;
  unsigned short* qb  = ws;                    // 4096*1024
  unsigned short* kb  = ws + 4194304;
  unsigned short* vb  = ws + 8388608;
  unsigned short* Wqb = ws + 12582912;         // 1024*1024 each
  unsigned short* Wkb = ws + 13631488;
  unsigned short* Wvb = ws + 14680064;
  unsigned short* Wob = ws + 15728640;
  unsigned short* Qp  = ws + 16777216;         // [B,H,S,D]
  unsigned short* Kp  = ws + 20971520;         // [B,H,S,D]
  unsigned short* Vt  = ws + 25165824;         // [B,H,D,S] key-permuted
  unsigned short* X2  = qb;                    // alias: qb dead after QKV GEMM

  // fp32 -> bf16 (2 fused launches)
  cvt3_kernel<<<dim3(4096, 3), 256, 0, stream>>>(
      (const float4*)q, (const float4*)k, (const float4*)v,
      (unsigned long long*)qb, (unsigned long long*)kb, (unsigned long long*)vb);
  cvt4_kernel<<<dim3(1024, 4), 256, 0, stream>>>(
      (const float4*)Wq, (const float4*)Wk, (const float4*)Wv, (const float4*)Wo,
      (unsigned long long*)Wqb, (unsigned long long*)Wkb,
      (unsigned long long*)Wvb, (unsigned long long*)Wob);

  // fused QKV projection: one 4096x3072 GEMM, 192 blocks x 512 threads
  qkv_gemm_kernel<<<dim3(192), 512, 0, stream>>>(
      qb, kb, vb, Wqb, Wkb, Wvb, bq, bk, bv, Qp, Kp, Vt);

  // banded attention -> X2 [B,S,E] bf16
  attn_kernel<<<1024, 256, 0, stream>>>(Qp, Kp, Vt, X2);

  // output projection -> fp32
  out_gemm_kernel<<<dim3(32, 8), 256, 0, stream>>>(X2, Wob, bo, out);
}

// Round 16
// 79.172 us; speedup vs baseline: 1.3333x; 1.0553x over previous
//
#include <hip/hip_runtime.h>
#include <hip/hip_bf16.h>

// Sliding-window attention, B=2 S=2048 E=1024 H=16 D=64 WINDOW=128.
// Pipeline: fp32->bf16 cvt (2 fused launches) -> fused QKV GEMM (single
// 4096x3072 GEMM, 256^2 tile, 8 waves, counted-vmcnt 2-barrier pipeline;
// V stored transposed + key-permuted) -> banded attention (128-q blocks,
// 8 waves, LDS-staged K/V, counted-vmcnt gates, swapped QK^T, lane-local
// softmax with v_cvt_pk pack, permuted-k PV) -> output GEMM (128^2,
// 8 waves, counted-vmcnt, fp32 out).

#define S_LEN 2048
#define EMB   1024
#define NHEAD 16
#define HDIM  64
#define MROWS 4096   // B*S

typedef __attribute__((ext_vector_type(4))) float f32x4;
typedef __attribute__((ext_vector_type(8))) short bf16x8;

__device__ __forceinline__ unsigned short f2bf(float x){
  union { float f; unsigned u; } un; un.f = x;
  unsigned u = un.u;
  unsigned r = (u + 0x7FFFu + ((u >> 16) & 1u)) >> 16;  // RNE
  return (unsigned short)r;
}

// packed RNE f32x2 -> bf16x2 (compiler emits v_cvt_pk_bf16_f32 on gfx950)
__device__ __forceinline__ unsigned cvtpk(float lo, float hi){
  __hip_bfloat162 h = __float22bfloat162_rn(make_float2(lo, hi));
  union { __hip_bfloat162 h2; unsigned u; } cv; cv.h2 = h;
  return cv.u;
}

// ---------------- fp32 -> bf16 conversion (fused, vectorized) ----------------
__global__ __launch_bounds__(256) void cvt3_kernel(
    const float4* __restrict__ s0, const float4* __restrict__ s1,
    const float4* __restrict__ s2,
    unsigned long long* __restrict__ d0, unsigned long long* __restrict__ d1,
    unsigned long long* __restrict__ d2)
{
  int i = blockIdx.x * 256 + threadIdx.x;
  const float4* s = (blockIdx.y == 0) ? s0 : (blockIdx.y == 1) ? s1 : s2;
  unsigned long long* d = (blockIdx.y == 0) ? d0 : (blockIdx.y == 1) ? d1 : d2;
  float4 v = s[i];
  d[i] = (unsigned long long)cvtpk(v.x, v.y)
       | ((unsigned long long)cvtpk(v.z, v.w) << 32);
}

__global__ __launch_bounds__(256) void cvt4_kernel(
    const float4* __restrict__ s0, const float4* __restrict__ s1,
    const float4* __restrict__ s2, const float4* __restrict__ s3,
    unsigned long long* __restrict__ d0, unsigned long long* __restrict__ d1,
    unsigned long long* __restrict__ d2, unsigned long long* __restrict__ d3)
{
  int i = blockIdx.x * 256 + threadIdx.x;
  const float4* s = (blockIdx.y == 0) ? s0 : (blockIdx.y == 1) ? s1 :
                    (blockIdx.y == 2) ? s2 : s3;
  unsigned long long* d = (blockIdx.y == 0) ? d0 : (blockIdx.y == 1) ? d1 :
                          (blockIdx.y == 2) ? d2 : d3;
  float4 v = s[i];
  d[i] = (unsigned long long)cvtpk(v.x, v.y)
       | ((unsigned long long)cvtpk(v.z, v.w) << 32);
}

// ---------------- async global->LDS (16B per lane) ----------------
__device__ __forceinline__ void async_copy16(const unsigned short* g, unsigned short* l){
  __builtin_amdgcn_global_load_lds(
      (const __attribute__((address_space(1))) unsigned int*)(const void*)g,
      (__attribute__((address_space(3))) unsigned int*)(void*)l,
      16, 0, 0);
}

// ---------------- fused QKV projection: one 4096x3072 GEMM ----------------
// 256x256 tile, BK=64, 8 waves (2M x 4N), 128KB dbuf LDS, counted-vmcnt
// pipeline with two barriers per K-tile (round-8 derivation).
// n < 1024: Q -> [B,H,S,D]; n < 2048: K -> [B,H,S,D];
// n < 3072: V -> transposed [B,H,D,S], keys permuted within 32-blocks:
//   pos(s) = (s&~31) | ((s>>2)&3)*8 | ((s>>4)&1)*4 | (s&3)
__global__ __launch_bounds__(512, 2) void qkv_gemm_kernel(
    const unsigned short* __restrict__ qb, const unsigned short* __restrict__ kb2,
    const unsigned short* __restrict__ vb,
    const unsigned short* __restrict__ Wqb, const unsigned short* __restrict__ Wkb,
    const unsigned short* __restrict__ Wvb,
    const float* __restrict__ bq, const float* __restrict__ bk,
    const float* __restrict__ bv,
    unsigned short* __restrict__ Qp, unsigned short* __restrict__ Kp,
    unsigned short* __restrict__ Vt)
{
  __shared__ __align__(16) unsigned short lds[2][2][256*64];  // [buf][A/B][r*64+k]

  const int tid = threadIdx.x, lane = tid & 63, wid = tid >> 6;  // wid 0..7
  const int wm = wid >> 2, wn = wid & 3;       // 2M x 4N wave grid
  const int c = lane & 15, g = lane >> 4;
  const int srow = lane >> 3, sch = lane & 7;

  // XCD swizzle over 192 blocks (192 % 8 == 0 -> bijective)
  int bid  = blockIdx.x;
  int bid2 = (bid & 7) * 24 + (bid >> 3);
  const int mx = bid2 & 15, ny = bid2 >> 4;    // 16 m-tiles x 12 n-tiles
  const int z  = ny >> 2;                      // 0:Q 1:K 2:V (block-uniform)
  const int tile_m = mx * 256;
  const int nloc   = (ny & 3) * 256;           // proj-local n base

  const unsigned short* A = (z == 0) ? qb  : (z == 1) ? kb2 : vb;
  const unsigned short* W = (z == 0) ? Wqb : (z == 1) ? Wkb : Wvb;
  const float*       bias = (z == 0) ? bq  : (z == 1) ? bk  : bv;

  const unsigned short* Asrc = A + (size_t)tile_m * EMB;
  const unsigned short* Bsrc = W + (size_t)nloc * EMB;

  f32x4 acc[8][4] = {};

  // chunk-p stage: 8 A-rows + 8 B-rows per wave (2 loads/thread)
  auto stageP = [&](int b, int k0, int p){
    int row = wid*32 + p*8 + srow;
    int ch  = sch ^ (row & 7);                 // pre-swizzled source chunk
    async_copy16(Asrc + (size_t)row*EMB + k0 + ch*8, &lds[b][0][(wid*32 + p*8)*64]);
    async_copy16(Bsrc + (size_t)row*EMB + k0 + ch*8, &lds[b][1][(wid*32 + p*8)*64]);
  };

  // prologue: tile 0 fully staged (8 loads/thread)
  stageP(0, 0, 0); stageP(0, 0, 1); stageP(0, 0, 2); stageP(0, 0, 3);

  for (int t = 0; t < 16; ++t){
    const int cb = t & 1, nb = cb ^ 1;
    const bool pre = (t < 15);
    const int k1 = (t + 1) * 64;

    // gate: tile t resident for all waves; 2 fresh loads stay in flight
    if (pre){
      stageP(nb, k1, 0);
      asm volatile("s_waitcnt vmcnt(2)" ::: "memory");
    } else {
      asm volatile("s_waitcnt vmcnt(0)" ::: "memory");
    }
    asm volatile("s_barrier" ::: "memory");

    // B-frags for the whole K-tile (held in regs across phases)
    bf16x8 bfr[4][2];
#pragma unroll
    for (int ni = 0; ni < 4; ++ni)
#pragma unroll
      for (int kk = 0; kk < 2; ++kk){
        int row = wn*64 + ni*16 + c;
        int ch  = (kk*4 + g) ^ (row & 7);
        bfr[ni][kk] = *(const bf16x8*)&lds[cb][1][row*64 + ch*8];
      }

#pragma unroll
    for (int p = 0; p < 4; ++p){
      bf16x8 af[2][2];
#pragma unroll
      for (int mi = 0; mi < 2; ++mi)
#pragma unroll
        for (int kk = 0; kk < 2; ++kk){
          int row = wm*128 + (p*2 + mi)*16 + c;
          int ch  = (kk*4 + g) ^ (row & 7);
          af[mi][kk] = *(const bf16x8*)&lds[cb][0][row*64 + ch*8];
        }
      if (pre && p < 3) stageP(nb, k1, p + 1);  // spread VMEM issue
      __builtin_amdgcn_s_setprio(1);
#pragma unroll
      for (int kk = 0; kk < 2; ++kk)
#pragma unroll
        for (int mi = 0; mi < 2; ++mi)
#pragma unroll
          for (int ni = 0; ni < 4; ++ni)
            acc[p*2 + mi][ni] = __builtin_amdgcn_mfma_f32_16x16x32_bf16(
                af[mi][kk], bfr[ni][kk], acc[p*2 + mi][ni], 0, 0, 0);
      __builtin_amdgcn_s_setprio(0);
    }
    // all waves done reading cb (ds_reads drained via MFMA deps above)
    asm volatile("s_barrier" ::: "memory");
  }

  // epilogue
  if (z < 2){
    unsigned short* O = (z == 0) ? Qp : Kp;
#pragma unroll
    for (int mf = 0; mf < 8; ++mf){
      int m0 = tile_m + wm*128 + mf*16 + g*4;
      int bb = m0 >> 11, ss = m0 & 2047;
#pragma unroll
      for (int ni = 0; ni < 4; ++ni){
        int nn = nloc + wn*64 + ni*16 + c;
        int h = nn >> 6, d = nn & 63;
        float bvn = bias[nn];
        size_t base = (((size_t)bb*NHEAD + h)*S_LEN + ss)*HDIM + d;
#pragma unroll
        for (int j = 0; j < 4; ++j)
          O[base + (size_t)j*HDIM] = f2bf(acc[mf][ni][j] + bvn);
      }
    }
  } else {
#pragma unroll
    for (int mf = 0; mf < 8; ++mf){
      int m0 = tile_m + wm*128 + mf*16 + g*4;
      int bb = m0 >> 11, ss = m0 & 2047;
      // key-permuted position (ss % 4 == 0, quad stays one 8B store)
      int ssp = (ss & ~31) | (((ss >> 2) & 3) << 3) | (((ss >> 4) & 1) << 2);
#pragma unroll
      for (int ni = 0; ni < 4; ++ni){
        int nn = nloc + wn*64 + ni*16 + c;
        int h = nn >> 6, d = nn & 63;
        float bvn = bias[nn];
        unsigned long long pk =
              (unsigned long long)cvtpk(acc[mf][ni][0] + bvn, acc[mf][ni][1] + bvn)
            | ((unsigned long long)cvtpk(acc[mf][ni][2] + bvn, acc[mf][ni][3] + bvn) << 32);
        *(unsigned long long*)&Vt[(((size_t)bb*NHEAD + h)*HDIM + d)*S_LEN + ssp] = pk;
      }
    }
  }
}

// ---------------- banded attention: 128-q blocks, 8 waves ----------------
// 1 block = (b,h, 128 q-rows); 8 waves x 16 q-rows; 64-key tiles shared by
// the block (6 per block vs 5 per 64-q block: -40% staging+barriers),
// double-buffered in LDS. Per tile: stage next (2 loads/thread) -> vmcnt(2)
// -> s_barrier -> compute cur (band-active waves only) -> s_barrier.
// Swapped QK^T, lane-local fixed-max softmax (v_cvt_pk pack), permuted-k PV.
__global__ __launch_bounds__(512) void attn_kernel(
    const unsigned short* __restrict__ Qp, const unsigned short* __restrict__ Kp,
    const unsigned short* __restrict__ Vt, unsigned short* __restrict__ X2)
{
  __shared__ __align__(16) unsigned short Kl[2][64*64];
  __shared__ __align__(16) unsigned short Vl[2][64*64];

  const int tid = threadIdx.x, lane = tid & 63, w = tid >> 6;   // w 0..7
  const int c = lane & 15, g = lane >> 4;
  // XCD swizzle (512 = 8 XCD x 64)
  int bid0 = blockIdx.x;
  int bid = (bid0 & 7) * 64 + (bid0 >> 3);
  const int bh = bid >> 4, qc = bid & 15;       // 32 bh x 16 chunks of 128 q
  const int qbase = qc * 128;
  const int qw = qbase + w * 16;
  const int qi = qw + c;

  const unsigned short* Kbh = Kp + (size_t)bh * S_LEN * HDIM;
  const unsigned short* Vbh = Vt + (size_t)bh * HDIM * S_LEN;

  const unsigned short* Qb = Qp + ((size_t)bh*S_LEN + qw + c)*HDIM;
  bf16x8 aq0 = *(const bf16x8*)(Qb + g*8);
  bf16x8 aq1 = *(const bf16x8*)(Qb + 32 + g*8);

  f32x4 accO[4] = {};
  float lsum = 0.f;
  const float SC = 0.18033688011112042f;  // (1/sqrt(64)) * log2(e)

  int t0 = qbase - 128; if (t0 < 0) t0 = 0;
  int t1 = qbase + 256; if (t1 > S_LEN) t1 = S_LEN;

  const int srow = lane >> 3;
  const int sch  = (lane & 7) ^ srow;

  auto stage = [&](int buf, int kt){           // 2 loads/thread (8 waves)
    int r0 = w * 8;
    async_copy16(Kbh + (size_t)(kt + r0 + srow)*HDIM + sch*8, &Kl[buf][r0*64]);
    async_copy16(Vbh + (size_t)(r0 + srow)*S_LEN + kt + sch*8, &Vl[buf][r0*64]);
  };

  auto compute = [&](int buf, int kt){
    f32x4 s[4];
    __builtin_amdgcn_s_setprio(1);
#pragma unroll
    for (int f = 0; f < 4; ++f){
      const unsigned short* Kr = &Kl[buf][(f*16 + c)*64];
      bf16x8 k0 = *(const bf16x8*)(Kr + ((    g) ^ (c & 7))*8);
      bf16x8 k1 = *(const bf16x8*)(Kr + ((4 + g) ^ (c & 7))*8);
      f32x4 a = {0.f, 0.f, 0.f, 0.f};
      a = __builtin_amdgcn_mfma_f32_16x16x32_bf16(k0, aq0, a, 0, 0, 0);
      a = __builtin_amdgcn_mfma_f32_16x16x32_bf16(k1, aq1, a, 0, 0, 0);
      s[f] = a;
    }
    __builtin_amdgcn_s_setprio(0);

    float p[4][4];
    bool nomask = (kt >= qw - 113) && (kt <= qw + 65);
    if (nomask){
#pragma unroll
      for (int f = 0; f < 4; ++f)
#pragma unroll
        for (int j = 0; j < 4; ++j){
          p[f][j] = __builtin_amdgcn_exp2f(s[f][j] * SC);
          lsum += p[f][j];
        }
    } else {
#pragma unroll
      for (int f = 0; f < 4; ++f)
#pragma unroll
        for (int j = 0; j < 4; ++j){
          int dlt = qi - (kt + f*16 + g*4 + j);
          float e = __builtin_amdgcn_exp2f(s[f][j] * SC);
          e = (dlt <= 128 && dlt >= -128) ? e : 0.f;
          p[f][j] = e;
          lsum += e;
        }
    }

    // pack p -> bf16 A-frags via v_cvt_pk_bf16_f32 (1 op per pair)
    union { unsigned u[4]; bf16x8 v; } A0, A1;
    A0.u[0] = cvtpk(p[0][0], p[0][1]);
    A0.u[1] = cvtpk(p[0][2], p[0][3]);
    A0.u[2] = cvtpk(p[1][0], p[1][1]);
    A0.u[3] = cvtpk(p[1][2], p[1][3]);
    A1.u[0] = cvtpk(p[2][0], p[2][1]);
    A1.u[1] = cvtpk(p[2][2], p[2][3]);
    A1.u[2] = cvtpk(p[3][0], p[3][1]);
    A1.u[3] = cvtpk(p[3][2], p[3][3]);

    __builtin_amdgcn_s_setprio(1);
#pragma unroll
    for (int dblk = 0; dblk < 4; ++dblk){
      const unsigned short* Vr = &Vl[buf][(dblk*16 + c)*64];
      bf16x8 v0 = *(const bf16x8*)(Vr + ((    g) ^ (c & 7))*8);
      bf16x8 v1 = *(const bf16x8*)(Vr + ((4 + g) ^ (c & 7))*8);
      accO[dblk] = __builtin_amdgcn_mfma_f32_16x16x32_bf16(A0.v, v0, accO[dblk], 0, 0, 0);
      accO[dblk] = __builtin_amdgcn_mfma_f32_16x16x32_bf16(A1.v, v1, accO[dblk], 0, 0, 0);
    }
    __builtin_amdgcn_s_setprio(0);
  };

  stage(0, t0);
  int cur = 0;
  for (int kt = t0; kt < t1; kt += 64){
    if (kt + 64 < t1){
      stage(cur ^ 1, kt + 64);
      asm volatile("s_waitcnt vmcnt(2)" ::: "memory");  // tile kt resident
    } else {
      asm volatile("s_waitcnt vmcnt(0)" ::: "memory");
    }
    asm volatile("s_barrier" ::: "memory");
    bool active = (kt + 63 >= qw - 128) && (kt <= qw + 143);  // wave-uniform
    if (active) compute(cur, kt);
    asm volatile("s_barrier" ::: "memory");   // cur free for overwrite
    cur ^= 1;
  }

  lsum += __shfl_xor(lsum, 16);
  lsum += __shfl_xor(lsum, 32);
  float rl[4];
#pragma unroll
  for (int j = 0; j < 4; ++j)
    rl[j] = 1.f / __shfl(lsum, g*4 + j);

  const int b_ = bh >> 4, h_ = bh & 15;
#pragma unroll
  for (int dblk = 0; dblk < 4; ++dblk)
#pragma unroll
    for (int j = 0; j < 4; ++j){
      int s_ = qw + g*4 + j, d_ = dblk*16 + c;
      X2[((size_t)(b_*S_LEN + s_))*EMB + h_*64 + d_] = f2bf(accO[dblk][j] * rl[j]);
    }
}

// ---------------- output projection (8 waves, fp32 out) ----------------
// 128^2 tile, 512 threads (2M x 4N waves, 64x32 output each): 2 waves/SIMD
// so the counted-vmcnt gate hides under co-resident waves.
__global__ __launch_bounds__(512) void out_gemm_kernel(
    const unsigned short* __restrict__ X2, const unsigned short* __restrict__ Wob,
    const float* __restrict__ bo, float* __restrict__ out)
{
  __shared__ __align__(16) unsigned short lds[4*8192];  // As0 Bs0 As1 Bs1
  const int tid = threadIdx.x, lane = tid & 63, wid = tid >> 6;  // 0..7
  const int wm = wid >> 2, wn = wid & 3;
  const int c = lane & 15, g = lane >> 4;
  const int srow = lane >> 3, sch = lane & 7;
  const int tile_m = blockIdx.x * 128;
  const int tile_n = blockIdx.y * 128;

  unsigned short* As0 = lds;
  unsigned short* Bs0 = lds + 8192;
  unsigned short* As1 = lds + 16384;
  unsigned short* Bs1 = lds + 24576;

  f32x4 acc[4][2] = {};

  auto stage = [&](unsigned short* As, unsigned short* Bs, int k0){
#pragma unroll
    for (int i = 0; i < 2; ++i){
      int row = (wid*2 + i)*8 + srow;
      int chg = sch ^ (row & 7);               // pre-swizzled source chunk
      async_copy16(X2  + (size_t)(tile_m + row)*EMB + k0 + chg*8, As + (wid*2 + i)*512);
      async_copy16(Wob + (size_t)(tile_n + row)*EMB + k0 + chg*8, Bs + (wid*2 + i)*512);
    }
  };

  auto compute = [&](const unsigned short* As, const unsigned short* Bs){
#pragma unroll
    for (int kk = 0; kk < 2; ++kk){
      bf16x8 af[4], bfv[2];
#pragma unroll
      for (int mi = 0; mi < 4; ++mi){
        int row = wm*64 + mi*16 + c;
        int ch  = (kk*4 + g) ^ (row & 7);
        af[mi] = *(const bf16x8*)&As[row*64 + ch*8];
      }
#pragma unroll
      for (int ni = 0; ni < 2; ++ni){
        int row = wn*32 + ni*16 + c;
        int ch  = (kk*4 + g) ^ (row & 7);
        bfv[ni] = *(const bf16x8*)&Bs[row*64 + ch*8];
      }
#pragma unroll
      for (int mi = 0; mi < 4; ++mi)
#pragma unroll
        for (int ni = 0; ni < 2; ++ni)
          acc[mi][ni] = __builtin_amdgcn_mfma_f32_16x16x32_bf16(af[mi], bfv[ni], acc[mi][ni], 0, 0, 0);
    }
  };

  stage(As0, Bs0, 0);
  for (int t = 0; t < 16; ++t){
    const unsigned short* Ac = (t & 1) ? As1 : As0;
    const unsigned short* Bc = (t & 1) ? Bs1 : Bs0;
    unsigned short*       An = (t & 1) ? As0 : As1;
    unsigned short*       Bn = (t & 1) ? Bs0 : Bs1;
    if (t < 15){
      stage(An, Bn, (t + 1) * 64);
      asm volatile("s_waitcnt vmcnt(4)" ::: "memory");  // tile t resident
    } else {
      asm volatile("s_waitcnt vmcnt(0)" ::: "memory");
    }
    asm volatile("s_barrier" ::: "memory");
    compute(Ac, Bc);
    asm volatile("s_barrier" ::: "memory");   // all waves done reading cur
  }

#pragma unroll
  for (int mi = 0; mi < 4; ++mi){
    int m0 = tile_m + wm*64 + mi*16 + g*4;
#pragma unroll
    for (int ni = 0; ni < 2; ++ni){
      int n = tile_n + wn*32 + ni*16 + c;
      float bvn = bo[n];
#pragma unroll
      for (int j = 0; j < 4; ++j)
        out[(size_t)(m0 + j)*EMB + n] = acc[mi][ni][j] + bvn;
    }
  }
}

extern "C" void kernel_launch(void* const* d_in, const int* in_sizes, int n_in,
                              void* d_out, int out_size, void* d_ws, size_t ws_size,
                              hipStream_t stream)
{
  const float* q  = (const float*)d_in[0];
  const float* k  = (const float*)d_in[1];
  const float* v  = (const float*)d_in[2];
  const float* Wq = (const float*)d_in[3];
  const float* bq = (const float*)d_in[4];
  const float* Wk = (const float*)d_in[5];
  const float* bk = (const float*)d_in[6];
  const float* Wv = (const float*)d_in[7];
  const float* bv = (const float*)d_in[8];
  const float* Wo = (const float*)d_in[9];
  const float* bo = (const float*)d_in[10];
  float* out = (float*)d_out;

  // workspace layout (ushort elements); total 56 MB
  unsigned short* ws = (unsigned short*)d_ws;
  unsigned short* qb  = ws;                    // 4096*1024
  unsigned short* kb  = ws + 4194304;
  unsigned short* vb  = ws + 8388608;
  unsigned short* Wqb = ws + 12582912;         // 1024*1024 each
  unsigned short* Wkb = ws + 13631488;
  unsigned short* Wvb = ws + 14680064;
  unsigned short* Wob = ws + 15728640;
  unsigned short* Qp  = ws + 16777216;         // [B,H,S,D]
  unsigned short* Kp  = ws + 20971520;         // [B,H,S,D]
  unsigned short* Vt  = ws + 25165824;         // [B,H,D,S] key-permuted
  unsigned short* X2  = qb;                    // alias: qb dead after QKV GEMM

  // fp32 -> bf16 (2 fused launches)
  cvt3_kernel<<<dim3(4096, 3), 256, 0, stream>>>(
      (const float4*)q, (const float4*)k, (const float4*)v,
      (unsigned long long*)qb, (unsigned long long*)kb, (unsigned long long*)vb);
  cvt4_kernel<<<dim3(1024, 4), 256, 0, stream>>>(
      (const float4*)Wq, (const float4*)Wk, (const float4*)Wv, (const float4*)Wo,
      (unsigned long long*)Wqb, (unsigned long long*)Wkb,
      (unsigned long long*)Wvb, (unsigned long long*)Wob);

  // fused QKV projection: one 4096x3072 GEMM, 192 blocks x 512 threads
  qkv_gemm_kernel<<<dim3(192), 512, 0, stream>>>(
      qb, kb, vb, Wqb, Wkb, Wvb, bq, bk, bv, Qp, Kp, Vt);

  // banded attention -> X2 [B,S,E] bf16; 512 blocks x 512 threads
  attn_kernel<<<512, 512, 0, stream>>>(Qp, Kp, Vt, X2);

  // output projection -> fp32; 256 blocks x 512 threads
  out_gemm_kernel<<<dim3(32, 8), 512, 0, stream>>>(X2, Wob, bo, out);
}